// Round 8
// baseline (106.434 us; speedup 1.0000x reference)
//
#include <hip/hip_runtime.h>

namespace {

constexpr int Cn = 80, NTGT = 200;
constexpr unsigned CH = 85;
constexpr unsigned S0 = 80, S1 = 40, S2 = 20;

constexpr unsigned F0 = 16u * 3u * 80u * 80u * 85u / 4u;   // 6,528,000 float4
constexpr unsigned F1 = 16u * 3u * 40u * 40u * 85u / 4u;   // 1,632,000
constexpr unsigned F2 = 16u * 3u * 20u * 20u * 85u / 4u;   //   408,000

constexpr unsigned BLOCK = 256;
constexpr unsigned NBLK  = 2048;                 // streaming blocks (8/CU)
constexpr unsigned STRIDE = NBLK * BLOCK;        // 524,288 float4 / iter
constexpr unsigned CSTEP  = (STRIDE * 4u) % CH;  // 32: channel advance per iter

constexpr float WO0 = 1.0f / (48.0f * 80.0f * 80.0f);
constexpr float WO1 = 1.0f / (48.0f * 40.0f * 40.0f);
constexpr float WO2 = 1.0f / (48.0f * 20.0f * 20.0f);
constexpr float WC0 = WO0 / 80.0f;
constexpr float WC1 = WO1 / 80.0f;
constexpr float WC2 = WO2 / 80.0f;

// Lean softplus: sp(x) = max(x,0) + log1p(e^{-|x|}); ~13 VALU, no v_exp/v_log.
__device__ __forceinline__ float softplus_lean(float x) {
    float s = fminf(fabsf(x) * 1.44269504f, 30.0f);
    int   n = (int)s;
    float f = s - (float)n;
    float q = fmaf(fmaf(0.171122f, f, -0.668647f), f, 0.998651f);      // ~2^{-f}
    float e2 = __int_as_float((127 - n) << 23);                        // 2^{-n}
    float u  = q * e2;                                                 // ~e^{-|x|}
    float p  = u * fmaf(fmaf(0.118988f, u, -0.415863f), u, 0.990022f); // ~log1p(u)
    return fmaxf(x, 0.0f) + p;
}

// One float4 with channel phase c0 (0..84) for its first element.
//   cls (5<=c<=84): (c0-(5-k)) unsigned< 80  [wrapped c>=85 lands in box 0..3]
//   obj (c==4):      c0 == 4-k               [wrap never yields 4]
__device__ __forceinline__ void proc4(const float4 v, unsigned c0,
                                      float& accO, float& accC)
{
    float vals[4] = {v.x, v.y, v.z, v.w};
    #pragma unroll
    for (unsigned k = 0; k < 4; ++k) {
        float sp = softplus_lean(vals[k]);
        accC += ((c0 - (5u - k)) < 80u) ? sp : 0.0f;
        accO += (c0 == (4u - k))        ? sp : 0.0f;
    }
}

__device__ __forceinline__ unsigned wrap85(unsigned c) {
    return (c >= CH) ? c - CH : c;
}

// One fused kernel: 2048 streaming blocks + 1 corr block, device-scope float
// atomics into acc[2], last-finisher (done-counter) writes the 4 outputs.
__global__ __launch_bounds__(BLOCK) void yolo_fused_kernel(
    const float* __restrict__ p0, const float* __restrict__ p1,
    const float* __restrict__ p2, const float* __restrict__ tgt,
    float* __restrict__ acc, unsigned* __restrict__ counter,
    float* __restrict__ out)
{
    __shared__ unsigned keyO[NTGT], keyC[NTGT];
    float accO = 0.0f, accC = 0.0f;   // this block's weighted contribution

    if (blockIdx.x < NBLK) {
        // ---- streaming path: grid-stride, depth-2 software pipeline ----
        unsigned tid = blockIdx.x * BLOCK + threadIdx.x;
        unsigned c0i = (tid * 4u) % CH;

        {   // tensor 0 (12-13 iters/thread)
            const float4* P = (const float4*)p0;
            float aO = 0.f, aC = 0.f; unsigned c0 = c0i;
            if (tid < F0) {
                float4 nxt = P[tid];
                for (unsigned j = tid + STRIDE; j < F0; j += STRIDE) {
                    float4 cur = nxt;
                    nxt = P[j];                   // in flight during proc4
                    proc4(cur, c0, aO, aC);
                    c0 = wrap85(c0 + CSTEP);
                }
                proc4(nxt, c0, aO, aC);
            }
            accO = fmaf(WO0, aO, accO); accC = fmaf(WC0, aC, accC);
        }
        {   // tensor 1 (3-4 iters/thread)
            const float4* P = (const float4*)p1;
            float aO = 0.f, aC = 0.f; unsigned c0 = c0i;
            if (tid < F1) {
                float4 nxt = P[tid];
                for (unsigned j = tid + STRIDE; j < F1; j += STRIDE) {
                    float4 cur = nxt;
                    nxt = P[j];
                    proc4(cur, c0, aO, aC);
                    c0 = wrap85(c0 + CSTEP);
                }
                proc4(nxt, c0, aO, aC);
            }
            accO = fmaf(WO1, aO, accO); accC = fmaf(WC1, aC, accC);
        }
        if (tid < F2) {  // tensor 2 (<=1 iter/thread)
            const float4* P = (const float4*)p2;
            float aO = 0.f, aC = 0.f;
            proc4(P[tid], c0i, aO, aC);
            accO = fmaf(WO2, aO, accO); accC = fmaf(WC2, aC, accC);
        }
    } else {
        // ---- corr block: dedup targets, subtract l*z at hot cells ----
        int t = threadIdx.x;
        float fb = 0.f, fc = 0.f, fx = 0.f, fy = 0.f;
        bool valid = false;
        if (t < NTGT) {
            fb = tgt[t * 6 + 0];
            fc = tgt[t * 6 + 1];
            fx = tgt[t * 6 + 2];
            fy = tgt[t * 6 + 3];
            valid = (fc < (float)Cn);
        }
        int b  = valid ? (int)fb : 0;
        int cl = valid ? (int)fc : 0;

        const float* preds[3] = {p0, p1, p2};
        const int    SS[3]    = {(int)S0, (int)S1, (int)S2};
        const float  WOs[3]   = {WO0, WO1, WO2};
        const float  WCs[3]   = {WC0, WC1, WC2};

        for (int s = 0; s < 3; ++s) {
            int W = SS[s];
            unsigned myO = 0x80000000u | (unsigned)t;  // unique sentinel
            unsigned myC = myO;
            float vObj = 0.f, vCls = 0.f;
            if (t < NTGT && valid) {
                int gx = min((int)floorf(fx * (float)W), W - 1);
                int gy = min((int)floorf(fy * (float)W), W - 1);
                myO = ((unsigned)b << 14) | ((unsigned)gy << 7) | (unsigned)gx;
                myC = (myO << 7) | (unsigned)cl;
                const float* P = preds[s];
                unsigned cell = ((unsigned)b * 3u * (unsigned)W + (unsigned)gy)
                                * (unsigned)W + (unsigned)gx;   // anchor a=0
                vObj = P[cell * CH + 4u];
                vCls = P[cell * CH + 5u + (unsigned)cl];
            }
            if (t < NTGT) { keyO[t] = myO; keyC[t] = myC; }
            __syncthreads();

            bool uo = true, uc = true;
            int lim = (t < NTGT) ? t : 0;
            #pragma unroll 4
            for (int j = 0; j < lim; ++j) {
                unsigned ko = keyO[j], kc = keyC[j];
                uo = uo && (ko != myO);
                uc = uc && (kc != myC);
            }
            if (t < NTGT && valid) {
                if (uo) accO -= vObj * WOs[s];
                if (uc) accC -= vCls * WCs[s];
            }
            __syncthreads();
        }
    }

    // ---- common block reduce + device-scope accumulate ----
    #pragma unroll
    for (int off = 32; off > 0; off >>= 1) {
        accO += __shfl_down(accO, off);
        accC += __shfl_down(accC, off);
    }
    __shared__ float sO[4], sC[4];
    int lane = threadIdx.x & 63, wv = threadIdx.x >> 6;
    if (lane == 0) { sO[wv] = accO; sC[wv] = accC; }
    __syncthreads();

    if (threadIdx.x == 0) {
        float o = sO[0] + sO[1] + sO[2] + sO[3];
        float c = sC[0] + sC[1] + sC[2] + sC[3];
        atomicAdd(&acc[0], o);               // device-scope by default
        atomicAdd(&acc[1], c);
        __threadfence();
        unsigned old = atomicAdd(counter, 1u);
        if (old == NBLK) {                   // last of NBLK+1 blocks
            __threadfence();
            float obj = __hip_atomic_load(&acc[0], __ATOMIC_RELAXED,
                                          __HIP_MEMORY_SCOPE_AGENT);
            float cls = __hip_atomic_load(&acc[1], __ATOMIC_RELAXED,
                                          __HIP_MEMORY_SCOPE_AGENT);
            out[0] = obj + 0.5f * cls;       // BOX_W*0 + OBJ_W*obj + CLS_W*cls
            out[1] = 0.0f;                   // total_box
            out[2] = obj;
            out[3] = cls;
        }
    }
}

}  // namespace

extern "C" void kernel_launch(void* const* d_in, const int* in_sizes, int n_in,
                              void* d_out, int out_size, void* d_ws, size_t ws_size,
                              hipStream_t stream)
{
    const float* p0  = (const float*)d_in[0];
    const float* p1  = (const float*)d_in[1];
    const float* p2  = (const float*)d_in[2];
    const float* tgt = (const float*)d_in[3];
    float* out = (float*)d_out;

    float*    acc     = (float*)d_ws;                       // acc[0], acc[1]
    unsigned* counter = (unsigned*)((char*)d_ws + 8);       // done-counter

    hipMemsetAsync(d_ws, 0, 12, stream);
    yolo_fused_kernel<<<NBLK + 1, BLOCK, 0, stream>>>(p0, p1, p2, tgt,
                                                      acc, counter, out);
}

// Round 9
// 104.570 us; speedup vs baseline: 1.0178x; 1.0178x over previous
//
#include <hip/hip_runtime.h>

namespace {

constexpr int Cn = 80, NTGT = 200;
constexpr unsigned CH = 85;
constexpr unsigned S0 = 80, S1 = 40, S2 = 20;

constexpr unsigned F0 = 16u * 3u * 80u * 80u * 85u / 4u;   // 6,528,000 float4
constexpr unsigned F1 = 16u * 3u * 40u * 40u * 85u / 4u;   // 1,632,000
constexpr unsigned F2 = 16u * 3u * 20u * 20u * 85u / 4u;   //   408,000

constexpr unsigned BLOCK   = 256;
constexpr unsigned NBLK    = 2048;              // total blocks (8/CU)
constexpr unsigned NSTREAM = NBLK - 1;          // 2047 streaming blocks
constexpr unsigned STRIDE  = NSTREAM * BLOCK;   // 524,032 float4 / iter
constexpr unsigned CSTEP   = (unsigned)((4ull * STRIDE) % CH);  // 28

constexpr float WO0 = 1.0f / (48.0f * 80.0f * 80.0f);
constexpr float WO1 = 1.0f / (48.0f * 40.0f * 40.0f);
constexpr float WO2 = 1.0f / (48.0f * 20.0f * 20.0f);
constexpr float WC0 = WO0 / 80.0f;
constexpr float WC1 = WO1 / 80.0f;
constexpr float WC2 = WO2 / 80.0f;

// Lean softplus: sp(x) = max(x,0) + log1p(e^{-|x|}); ~13 VALU, no v_exp/v_log.
__device__ __forceinline__ float softplus_lean(float x) {
    float s = fminf(fabsf(x) * 1.44269504f, 30.0f);
    int   n = (int)s;
    float f = s - (float)n;
    float q = fmaf(fmaf(0.171122f, f, -0.668647f), f, 0.998651f);      // ~2^{-f}
    float e2 = __int_as_float((127 - n) << 23);                        // 2^{-n}
    float u  = q * e2;                                                 // ~e^{-|x|}
    float p  = u * fmaf(fmaf(0.118988f, u, -0.415863f), u, 0.990022f); // ~log1p(u)
    return fmaxf(x, 0.0f) + p;
}

// One float4 with channel phase c0 (0..84) for its first element.
//   cls (5<=c<=84): (c0-(5-k)) unsigned< 80  [wrapped c>=85 lands in box 0..3]
//   obj (c==4):      c0 == 4-k               [wrap never yields 4]
__device__ __forceinline__ void proc4(const float4 v, unsigned c0,
                                      float& accO, float& accC)
{
    float vals[4] = {v.x, v.y, v.z, v.w};
    #pragma unroll
    for (unsigned k = 0; k < 4; ++k) {
        float sp = softplus_lean(vals[k]);
        accC += ((c0 - (5u - k)) < 80u) ? sp : 0.0f;
        accO += (c0 == (4u - k))        ? sp : 0.0f;
    }
}

__device__ __forceinline__ unsigned wrap85(unsigned c) {
    return (c >= CH) ? c - CH : c;
}

// 2047 streaming blocks (plain compiler-scheduled grid-stride loops — the
// round-6 shape; do NOT hand-pipeline, see round-8 post-mortem) + 1 corr
// block running CONCURRENTLY; device-scope float atomics into acc[2]; the
// last finisher (atomic done-counter) writes the 4 outputs.
__global__ __launch_bounds__(BLOCK) void yolo_fused_kernel(
    const float* __restrict__ p0, const float* __restrict__ p1,
    const float* __restrict__ p2, const float* __restrict__ tgt,
    float* __restrict__ acc, unsigned* __restrict__ counter,
    float* __restrict__ out)
{
    float accO = 0.0f, accC = 0.0f;   // this block's weighted contribution

    if (blockIdx.x < NSTREAM) {
        // ---- streaming path: plain grid-stride, one load per iteration ----
        unsigned tid = blockIdx.x * BLOCK + threadIdx.x;
        unsigned c0i = (tid * 4u) % CH;

        {   // tensor 0 (~12.5 iters/thread)
            const float4* P = (const float4*)p0;
            float aO = 0.f, aC = 0.f; unsigned c0 = c0i;
            for (unsigned i = tid; i < F0; i += STRIDE) {
                proc4(P[i], c0, aO, aC);
                c0 = wrap85(c0 + CSTEP);
            }
            accO = fmaf(WO0, aO, accO); accC = fmaf(WC0, aC, accC);
        }
        {   // tensor 1 (~3.1 iters/thread)
            const float4* P = (const float4*)p1;
            float aO = 0.f, aC = 0.f; unsigned c0 = c0i;
            for (unsigned i = tid; i < F1; i += STRIDE) {
                proc4(P[i], c0, aO, aC);
                c0 = wrap85(c0 + CSTEP);
            }
            accO = fmaf(WO1, aO, accO); accC = fmaf(WC1, aC, accC);
        }
        {   // tensor 2 (<=1 iter/thread)
            const float4* P = (const float4*)p2;
            float aO = 0.f, aC = 0.f; unsigned c0 = c0i;
            for (unsigned i = tid; i < F2; i += STRIDE) {
                proc4(P[i], c0, aO, aC);
                c0 = wrap85(c0 + CSTEP);
            }
            accO = fmaf(WO2, aO, accO); accC = fmaf(WC2, aC, accC);
        }
    } else {
        // ---- corr block (runs concurrently from t=0): dedup targets per
        // cell via packed u32 keys, subtract l*z at the hot cells ----
        __shared__ unsigned keyO[NTGT], keyC[NTGT];

        int t = threadIdx.x;
        float fb = 0.f, fc = 0.f, fx = 0.f, fy = 0.f;
        bool valid = false;
        if (t < NTGT) {
            fb = tgt[t * 6 + 0];
            fc = tgt[t * 6 + 1];
            fx = tgt[t * 6 + 2];
            fy = tgt[t * 6 + 3];
            valid = (fc < (float)Cn);
        }
        int b  = valid ? (int)fb : 0;
        int cl = valid ? (int)fc : 0;

        const float* preds[3] = {p0, p1, p2};
        const int    SS[3]    = {(int)S0, (int)S1, (int)S2};
        const float  WOs[3]   = {WO0, WO1, WO2};
        const float  WCs[3]   = {WC0, WC1, WC2};

        for (int s = 0; s < 3; ++s) {
            int W = SS[s];
            unsigned myO = 0x80000000u | (unsigned)t;  // unique sentinel
            unsigned myC = myO;
            float vObj = 0.f, vCls = 0.f;
            if (t < NTGT && valid) {
                int gx = min((int)floorf(fx * (float)W), W - 1);
                int gy = min((int)floorf(fy * (float)W), W - 1);
                myO = ((unsigned)b << 14) | ((unsigned)gy << 7) | (unsigned)gx;
                myC = (myO << 7) | (unsigned)cl;
                const float* P = preds[s];
                unsigned cell = ((unsigned)b * 3u * (unsigned)W + (unsigned)gy)
                                * (unsigned)W + (unsigned)gx;   // anchor a=0
                vObj = P[cell * CH + 4u];
                vCls = P[cell * CH + 5u + (unsigned)cl];
            }
            if (t < NTGT) { keyO[t] = myO; keyC[t] = myC; }
            __syncthreads();

            bool uo = true, uc = true;
            int lim = (t < NTGT) ? t : 0;
            #pragma unroll 4
            for (int j = 0; j < lim; ++j) {
                unsigned ko = keyO[j], kc = keyC[j];
                uo = uo && (ko != myO);
                uc = uc && (kc != myC);
            }
            if (t < NTGT && valid) {
                if (uo) accO -= vObj * WOs[s];
                if (uc) accC -= vCls * WCs[s];
            }
            __syncthreads();
        }
    }

    // ---- common block reduce + device-scope accumulate ----
    #pragma unroll
    for (int off = 32; off > 0; off >>= 1) {
        accO += __shfl_down(accO, off);
        accC += __shfl_down(accC, off);
    }
    __shared__ float sO[4], sC[4];
    int lane = threadIdx.x & 63, wv = threadIdx.x >> 6;
    if (lane == 0) { sO[wv] = accO; sC[wv] = accC; }
    __syncthreads();

    if (threadIdx.x == 0) {
        float o = sO[0] + sO[1] + sO[2] + sO[3];
        float c = sC[0] + sC[1] + sC[2] + sC[3];
        atomicAdd(&acc[0], o);               // device-scope by default
        atomicAdd(&acc[1], c);
        __threadfence();
        unsigned old = atomicAdd(counter, 1u);
        if (old == NBLK - 1u) {              // last of NBLK blocks
            __threadfence();
            float obj = __hip_atomic_load(&acc[0], __ATOMIC_RELAXED,
                                          __HIP_MEMORY_SCOPE_AGENT);
            float cls = __hip_atomic_load(&acc[1], __ATOMIC_RELAXED,
                                          __HIP_MEMORY_SCOPE_AGENT);
            out[0] = obj + 0.5f * cls;       // BOX_W*0 + OBJ_W*obj + CLS_W*cls
            out[1] = 0.0f;                   // total_box
            out[2] = obj;
            out[3] = cls;
        }
    }
}

}  // namespace

extern "C" void kernel_launch(void* const* d_in, const int* in_sizes, int n_in,
                              void* d_out, int out_size, void* d_ws, size_t ws_size,
                              hipStream_t stream)
{
    const float* p0  = (const float*)d_in[0];
    const float* p1  = (const float*)d_in[1];
    const float* p2  = (const float*)d_in[2];
    const float* tgt = (const float*)d_in[3];
    float* out = (float*)d_out;

    float*    acc     = (float*)d_ws;                       // acc[0], acc[1]
    unsigned* counter = (unsigned*)((char*)d_ws + 8);       // done-counter

    hipMemsetAsync(d_ws, 0, 12, stream);
    yolo_fused_kernel<<<NBLK, BLOCK, 0, stream>>>(p0, p1, p2, tgt,
                                                  acc, counter, out);
}

// Round 10
// 39.898 us; speedup vs baseline: 2.6677x; 2.6210x over previous
//
#include <hip/hip_runtime.h>

namespace {

constexpr int Cn = 80, NTGT = 200;
constexpr unsigned CH = 85;
constexpr unsigned S0 = 80, S1 = 40, S2 = 20;

constexpr unsigned F0 = 16u * 3u * 80u * 80u * 85u / 4u;   // 6,528,000 float4
constexpr unsigned F1 = 16u * 3u * 40u * 40u * 85u / 4u;   // 1,632,000
constexpr unsigned F2 = 16u * 3u * 20u * 20u * 85u / 4u;   //   408,000

constexpr unsigned BLOCK   = 256;
constexpr unsigned NBLK    = 2048;              // total blocks (8/CU)
constexpr unsigned NSTREAM = NBLK - 1;          // 2047 streaming blocks
constexpr unsigned STRIDE  = NSTREAM * BLOCK;   // 524,032 float4 / iter
constexpr unsigned CSTEP   = (unsigned)((4ull * STRIDE) % CH);  // 28

constexpr float WO0 = 1.0f / (48.0f * 80.0f * 80.0f);
constexpr float WO1 = 1.0f / (48.0f * 40.0f * 40.0f);
constexpr float WO2 = 1.0f / (48.0f * 20.0f * 20.0f);
constexpr float WC0 = WO0 / 80.0f;
constexpr float WC1 = WO1 / 80.0f;
constexpr float WC2 = WO2 / 80.0f;

// Lean softplus: sp(x) = max(x,0) + log1p(e^{-|x|}); ~13 VALU, no v_exp/v_log.
__device__ __forceinline__ float softplus_lean(float x) {
    float s = fminf(fabsf(x) * 1.44269504f, 30.0f);
    int   n = (int)s;
    float f = s - (float)n;
    float q = fmaf(fmaf(0.171122f, f, -0.668647f), f, 0.998651f);      // ~2^{-f}
    float e2 = __int_as_float((127 - n) << 23);                        // 2^{-n}
    float u  = q * e2;                                                 // ~e^{-|x|}
    float p  = u * fmaf(fmaf(0.118988f, u, -0.415863f), u, 0.990022f); // ~log1p(u)
    return fmaxf(x, 0.0f) + p;
}

// One float4 with channel phase c0 (0..84) for its first element.
//   cls (5<=c<=84): (c0-(5-k)) unsigned< 80  [wrapped c>=85 lands in box 0..3]
//   obj (c==4):      c0 == 4-k               [wrap never yields 4]
__device__ __forceinline__ void proc4(const float4 v, unsigned c0,
                                      float& accO, float& accC)
{
    float vals[4] = {v.x, v.y, v.z, v.w};
    #pragma unroll
    for (unsigned k = 0; k < 4; ++k) {
        float sp = softplus_lean(vals[k]);
        accC += ((c0 - (5u - k)) < 80u) ? sp : 0.0f;
        accO += (c0 == (4u - k))        ? sp : 0.0f;
    }
}

__device__ __forceinline__ unsigned wrap85(unsigned c) {
    return (c >= CH) ? c - CH : c;
}

// Blocks 0..NSTREAM-1: plain compiler-scheduled grid-stride streaming (the
// proven round-6 shape; no hand pipeline, no atomics). Block NSTREAM: corr
// dedup, running concurrently. Every block writes its OWN part[] slot.
__global__ __launch_bounds__(BLOCK) void yolo_fused_kernel(
    const float* __restrict__ p0, const float* __restrict__ p1,
    const float* __restrict__ p2, const float* __restrict__ tgt,
    float2* __restrict__ part)
{
    float accO = 0.0f, accC = 0.0f;   // this block's weighted contribution

    if (blockIdx.x < NSTREAM) {
        unsigned tid = blockIdx.x * BLOCK + threadIdx.x;
        unsigned c0i = (tid * 4u) % CH;

        {   // tensor 0 (~12.5 iters/thread)
            const float4* P = (const float4*)p0;
            float aO = 0.f, aC = 0.f; unsigned c0 = c0i;
            for (unsigned i = tid; i < F0; i += STRIDE) {
                proc4(P[i], c0, aO, aC);
                c0 = wrap85(c0 + CSTEP);
            }
            accO = fmaf(WO0, aO, accO); accC = fmaf(WC0, aC, accC);
        }
        {   // tensor 1 (~3.1 iters/thread)
            const float4* P = (const float4*)p1;
            float aO = 0.f, aC = 0.f; unsigned c0 = c0i;
            for (unsigned i = tid; i < F1; i += STRIDE) {
                proc4(P[i], c0, aO, aC);
                c0 = wrap85(c0 + CSTEP);
            }
            accO = fmaf(WO1, aO, accO); accC = fmaf(WC1, aC, accC);
        }
        {   // tensor 2 (<=1 iter/thread)
            const float4* P = (const float4*)p2;
            float aO = 0.f, aC = 0.f; unsigned c0 = c0i;
            for (unsigned i = tid; i < F2; i += STRIDE) {
                proc4(P[i], c0, aO, aC);
                c0 = wrap85(c0 + CSTEP);
            }
            accO = fmaf(WO2, aO, accO); accC = fmaf(WC2, aC, accC);
        }
    } else {
        // ---- corr block (concurrent): dedup targets per cell via packed
        // u32 keys, subtract l*z at the <=200 hot cells per scale ----
        __shared__ unsigned keyO[NTGT], keyC[NTGT];

        int t = threadIdx.x;
        float fb = 0.f, fc = 0.f, fx = 0.f, fy = 0.f;
        bool valid = false;
        if (t < NTGT) {
            fb = tgt[t * 6 + 0];
            fc = tgt[t * 6 + 1];
            fx = tgt[t * 6 + 2];
            fy = tgt[t * 6 + 3];
            valid = (fc < (float)Cn);
        }
        int b  = valid ? (int)fb : 0;
        int cl = valid ? (int)fc : 0;

        const float* preds[3] = {p0, p1, p2};
        const int    SS[3]    = {(int)S0, (int)S1, (int)S2};
        const float  WOs[3]   = {WO0, WO1, WO2};
        const float  WCs[3]   = {WC0, WC1, WC2};

        for (int s = 0; s < 3; ++s) {
            int W = SS[s];
            unsigned myO = 0x80000000u | (unsigned)t;  // unique sentinel
            unsigned myC = myO;
            float vObj = 0.f, vCls = 0.f;
            if (t < NTGT && valid) {
                int gx = min((int)floorf(fx * (float)W), W - 1);
                int gy = min((int)floorf(fy * (float)W), W - 1);
                myO = ((unsigned)b << 14) | ((unsigned)gy << 7) | (unsigned)gx;
                myC = (myO << 7) | (unsigned)cl;
                const float* P = preds[s];
                unsigned cell = ((unsigned)b * 3u * (unsigned)W + (unsigned)gy)
                                * (unsigned)W + (unsigned)gx;   // anchor a=0
                vObj = P[cell * CH + 4u];
                vCls = P[cell * CH + 5u + (unsigned)cl];
            }
            if (t < NTGT) { keyO[t] = myO; keyC[t] = myC; }
            __syncthreads();

            bool uo = true, uc = true;
            int lim = (t < NTGT) ? t : 0;
            #pragma unroll 4
            for (int j = 0; j < lim; ++j) {
                unsigned ko = keyO[j], kc = keyC[j];
                uo = uo && (ko != myO);
                uc = uc && (kc != myC);
            }
            if (t < NTGT && valid) {
                if (uo) accO -= vObj * WOs[s];
                if (uc) accC -= vCls * WCs[s];
            }
            __syncthreads();
        }
    }

    // ---- block reduce, then ONE private slot write (no atomics) ----
    #pragma unroll
    for (int off = 32; off > 0; off >>= 1) {
        accO += __shfl_down(accO, off);
        accC += __shfl_down(accC, off);
    }
    __shared__ float sO[4], sC[4];
    int lane = threadIdx.x & 63, wv = threadIdx.x >> 6;
    if (lane == 0) { sO[wv] = accO; sC[wv] = accC; }
    __syncthreads();
    if (threadIdx.x == 0)
        part[blockIdx.x] = make_float2(sO[0] + sO[1] + sO[2] + sO[3],
                                       sC[0] + sC[1] + sC[2] + sC[3]);
}

__global__ __launch_bounds__(BLOCK) void yolo_final_kernel(
    const float2* __restrict__ part, float* __restrict__ out)
{
    float o = 0.0f, c = 0.0f;
    for (unsigned i = threadIdx.x; i < NBLK; i += BLOCK) {
        float2 p = part[i];
        o += p.x; c += p.y;
    }
    #pragma unroll
    for (int off = 32; off > 0; off >>= 1) {
        o += __shfl_down(o, off);
        c += __shfl_down(c, off);
    }
    __shared__ float sO[4], sC[4];
    int lane = threadIdx.x & 63, wv = threadIdx.x >> 6;
    if (lane == 0) { sO[wv] = o; sC[wv] = c; }
    __syncthreads();
    if (threadIdx.x == 0) {
        float obj = sO[0] + sO[1] + sO[2] + sO[3];
        float cls = sC[0] + sC[1] + sC[2] + sC[3];
        out[0] = obj + 0.5f * cls;   // BOX_W*0 + OBJ_W*obj + CLS_W*cls
        out[1] = 0.0f;               // total_box
        out[2] = obj;
        out[3] = cls;
    }
}

}  // namespace

extern "C" void kernel_launch(void* const* d_in, const int* in_sizes, int n_in,
                              void* d_out, int out_size, void* d_ws, size_t ws_size,
                              hipStream_t stream)
{
    const float* p0  = (const float*)d_in[0];
    const float* p1  = (const float*)d_in[1];
    const float* p2  = (const float*)d_in[2];
    const float* tgt = (const float*)d_in[3];
    float* out = (float*)d_out;
    float2* part = (float2*)d_ws;   // NBLK per-block partials

    yolo_fused_kernel<<<NBLK, BLOCK, 0, stream>>>(p0, p1, p2, tgt, part);
    yolo_final_kernel<<<1,    BLOCK, 0, stream>>>(part, out);
}